// Round 11
// baseline (2897.072 us; speedup 1.0000x reference)
//
#include <hip/hip_runtime.h>
#include <stdint.h>

// ResRnn persistent kernel. R11: 8-wave WGs (512 thr), K-split 8.
//  - Weights now 128 VGPRs/wave (was 256): frees ~120 regs so all 16 A-loads
//    stage into registers BEFORE the MFMA loop -> one LLC latency per phase
//    instead of several (R6/R8 were reg-starved at VGPR_Count=256).
//  - Per-wave MFMA chain halves (32 vs 64). LDS reduce over 8 waves.
//  - Flags per (chunk, producer-wave): consumer wave polls its 8-chunk x
//    8-wave window (64 flags) in one lane-parallel load + ballot.
//  - Exchange: relaxed agent sc1 write-through stores + LLC-direct loads
//    (proven R4-R8); ping-pong depth 2 (wave-window unions cover all chunks
//    -> same transitivity safety proof).
//  - Trims: chunks 62/63 skip phase-2 for t<127; chunks<62 skip it at t=127.

#define NSTEPS 128
#define NB 128
#define WID 2048
#define SS 1984

#define SFN (128 * 1984)   // floats per Sf slot
#define SBN (128 * 1984)   // shorts per Sb slot
#define HN  (128 * 2048)   // shorts per h slot

typedef __attribute__((ext_vector_type(8))) short short8;
typedef __attribute__((ext_vector_type(4))) float f32x4;
typedef unsigned long long u64;

static __device__ __forceinline__ short f2bf(float f) {
  union { float f; unsigned u; } v; v.f = f;
  unsigned r = (v.u + 0x7fffu + ((v.u >> 16) & 1u)) >> 16;  // RNE
  return (short)r;
}
static __device__ __forceinline__ short8 pack8(f32x4 lo, f32x4 hi) {
  short8 r;
  r[0] = f2bf(lo[0]); r[1] = f2bf(lo[1]); r[2] = f2bf(lo[2]); r[3] = f2bf(lo[3]);
  r[4] = f2bf(hi[0]); r[5] = f2bf(hi[1]); r[6] = f2bf(hi[2]); r[7] = f2bf(hi[3]);
  return r;
}
static __device__ __forceinline__ void ast64(void* p, u64 v) {
  __hip_atomic_store((u64*)p, v, __ATOMIC_RELAXED, __HIP_MEMORY_SCOPE_AGENT);
}
static __device__ __forceinline__ void ast32(unsigned* p, unsigned v) {
  __hip_atomic_store(p, v, __ATOMIC_RELAXED, __HIP_MEMORY_SCOPE_AGENT);
}
static __device__ __forceinline__ u64 ald64(const void* p) {
  return __hip_atomic_load((const u64*)p, __ATOMIC_RELAXED, __HIP_MEMORY_SCOPE_AGENT);
}
static __device__ __forceinline__ unsigned ald32(const unsigned* p) {
  return __hip_atomic_load(p, __ATOMIC_RELAXED, __HIP_MEMORY_SCOPE_AGENT);
}
static __device__ __forceinline__ short8 ald_s8(const void* p) {
  union { u64 u[2]; short8 s; } r;
  r.u[0] = ald64((const char*)p); r.u[1] = ald64((const char*)p + 8);
  return r.s;
}

// wave-wide window wait: lane watches one flag; invalid lanes auto-pass.
static __device__ __forceinline__ void wwait(const unsigned* p, bool ok, unsigned tgt) {
  for (;;) {
    unsigned v = ok ? ald32(p) : tgt;
    if (__ballot(v >= tgt) == ~0ull) break;
    __builtin_amdgcn_s_sleep(1);
  }
}

__global__ __launch_bounds__(512, 2)
void resrnn_kernel(const float* __restrict__ inp, const float* __restrict__ W1,
                   const float* __restrict__ b1f, const float* __restrict__ W2,
                   const float* __restrict__ b2f, float* __restrict__ out,
                   unsigned char* __restrict__ ws)
{
  const int tid   = threadIdx.x;
  const int bid   = blockIdx.x;
  const int group = bid & 3;         // 4 independent batch groups (32 rows)
  const int chunk = bid >> 2;        // 64 N-chunks of 32 cols
  const int mbase = group * 32;
  const int n0    = chunk * 32;
  const int wave  = tid >> 6;        // 0..7
  const int lane  = tid & 63;
  const int l15   = lane & 15;
  const int q8    = (lane >> 4) * 8;
  const int kb    = wave * 256;      // K split 8 ways across waves

  // per-group flag arrays: slot (chunk*8 + producer_wave) x 16B, monotone gen.
  unsigned* sflags = (unsigned*)(ws + group * 16384);          // 8 KB
  unsigned* hflags = (unsigned*)(ws + group * 16384 + 8192);   // 8 KB
  float* SfR = (float*)(ws + 65536);
  short* SbR = (short*)(ws + 65536 + (size_t)2 * SFN * 4);
  short* hbR = (short*)(ws + 65536 + (size_t)2 * SFN * 4 + (size_t)2 * SBN * 2);

  __shared__ float red[8][16][65];   // 33.3 KB, +1 pad

  // ---- one-time: weight B-fragments into registers (128 VGPRs/wave) ----
  short8 B1[8][2], B2[8][2];
#pragma unroll
  for (int ks = 0; ks < 8; ++ks) {
#pragma unroll
    for (int nt = 0; nt < 2; ++nt) {
      const float* p1 = W1 + (size_t)(n0 + nt * 16 + l15) * WID + (kb + ks * 32 + q8);
      B1[ks][nt] = pack8(*(const f32x4*)p1, *(const f32x4*)(p1 + 4));
      const float* p2 = W2 + (size_t)(n0 + nt * 16 + l15) * WID + (kb + ks * 32 + q8);
      B2[ks][nt] = pack8(*(const f32x4*)p2, *(const f32x4*)(p2 + 4));
    }
  }

  const int m0 = mbase + l15;        // A rows 0-15
  const int m1 = mbase + 16 + l15;   // A rows 16-31
  const int o    = tid * 2;          // epilogue: 2 outputs/thread (1024 = 32x32)
  const int ml   = o >> 5;           // 0..31 ; wave w covers rows 4w..4w+3
  const int nl   = o & 31;           // even; nl/nl+1 never cross a 16-boundary
  const int mrow = mbase + ml;
  const int ridx  = (ml >> 4) * 8 + (nl >> 4) * 4 + (ml & 3);
  const int lidx0 = ((ml >> 2) & 3) * 16 + (nl & 15);
  const float b1a = b1f[n0 + nl], b1b = b1f[n0 + nl + 1];
  const float b2a = b2f[n0 + nl], b2b = b2f[n0 + nl + 1];

  // poll setup: lane watches producer (window-chunk = lane>>3, wave = lane&7)
  const int wwv = lane & 7;
  const int wc  = lane >> 3;                     // 0..7
  const int c1  = 8 * wave - 2 + wc;             // S window: chunks 8w-2..8w+5
  const bool ok1 = (c1 >= 0) && (c1 < 62);
  const unsigned* p1p = sflags + ((ok1 ? c1 : 0) * 8 + wwv) * 4;
  const int c2  = 8 * wave + wc;                 // h window: chunks 8w..8w+7
  const unsigned* p2p = hflags + (c2 * 8 + wwv) * 4;

#pragma unroll 1
  for (int t = 0; t < NSTEPS; ++t) {
    const int sW = t & 1, sR = sW ^ 1;
    float*       SfNew = SfR + (size_t)sW * SFN;
    const float* SfOld = SfR + (size_t)sR * SFN;
    const short* SbOld = SbR + (size_t)sR * SBN;
    short*       SbNew = SbR + (size_t)sW * SBN;
    short*       hb    = hbR + (size_t)sW * HN;

    // ============ phase 1: u = s@W1^T ; h = |u+b1| ============
    if (t > 0) wwait(p1p, ok1, (unsigned)t);
    short8 xa[8], xb[8];
#pragma unroll
    for (int ks = 0; ks < 8; ++ks) {             // stage ALL loads first
      if (kb == 0 && ks < 2) {
        const float* p0 = inp + ((size_t)t * NB + m0) * 64 + (ks * 32 + q8);
        const float* p1 = inp + ((size_t)t * NB + m1) * 64 + (ks * 32 + q8);
        xa[ks] = pack8(*(const f32x4*)p0, *(const f32x4*)(p0 + 4));
        xb[ks] = pack8(*(const f32x4*)p1, *(const f32x4*)(p1 + 4));
      } else if (t > 0) {
        xa[ks] = ald_s8(SbOld + (size_t)m0 * SS + (kb + ks * 32 - 64 + q8));
        xb[ks] = ald_s8(SbOld + (size_t)m1 * SS + (kb + ks * 32 - 64 + q8));
      }
    }
    f32x4 a00{}, a01{}, a10{}, a11{};
#pragma unroll
    for (int ks = 0; ks < 8; ++ks) {
      if ((kb == 0 && ks < 2) || t > 0) {
        a00 = __builtin_amdgcn_mfma_f32_16x16x32_bf16(xa[ks], B1[ks][0], a00, 0, 0, 0);
        a01 = __builtin_amdgcn_mfma_f32_16x16x32_bf16(xa[ks], B1[ks][1], a01, 0, 0, 0);
        a10 = __builtin_amdgcn_mfma_f32_16x16x32_bf16(xb[ks], B1[ks][0], a10, 0, 0, 0);
        a11 = __builtin_amdgcn_mfma_f32_16x16x32_bf16(xb[ks], B1[ks][1], a11, 0, 0, 0);
      }
    }
#pragma unroll
    for (int r = 0; r < 4; ++r) {                // ridx = mt*8 + nt*4 + r
      red[wave][r][lane]      = a00[r];
      red[wave][4 + r][lane]  = a01[r];
      red[wave][8 + r][lane]  = a10[r];
      red[wave][12 + r][lane] = a11[r];
    }
    __syncthreads();   // also gates epilogue behind the WG-wide union of S-waits
    {
      float s0 = b1a, s1 = b1b;
#pragma unroll
      for (int w = 0; w < 8; ++w) {
        s0 += red[w][ridx][lidx0];
        s1 += red[w][ridx][lidx0 + 1];
      }
      unsigned hu = (unsigned)(unsigned short)f2bf(fabsf(s0))
                  | ((unsigned)(unsigned short)f2bf(fabsf(s1)) << 16);
      ast32((unsigned*)(hb + (size_t)mrow * WID + (n0 + nl)), hu);
    }
    asm volatile("s_waitcnt vmcnt(0)" ::: "memory");   // this wave's rows at LLC
    if (lane == 0)
      ast32(hflags + (chunk * 8 + wave) * 4, (unsigned)t + 1);
    __syncthreads();   // red reuse barrier

    // ============ phase 2: g = h@W2^T ; state update ============
    const bool doP2 = (t < NSTEPS - 1) ? (chunk < 62) : (chunk >= 62);
    if (doP2) {
      wwait(p2p, true, (unsigned)t + 1);
      const short* h0 = hb + (size_t)m0 * WID + kb + q8;
      const short* h1 = hb + (size_t)m1 * WID + kb + q8;
#pragma unroll
      for (int ks = 0; ks < 8; ++ks) {           // stage ALL loads first
        xa[ks] = ald_s8(h0 + ks * 32);
        xb[ks] = ald_s8(h1 + ks * 32);
      }
      f32x4 c00{}, c01{}, c10{}, c11{};
#pragma unroll
      for (int ks = 0; ks < 8; ++ks) {
        c00 = __builtin_amdgcn_mfma_f32_16x16x32_bf16(xa[ks], B2[ks][0], c00, 0, 0, 0);
        c01 = __builtin_amdgcn_mfma_f32_16x16x32_bf16(xa[ks], B2[ks][1], c01, 0, 0, 0);
        c10 = __builtin_amdgcn_mfma_f32_16x16x32_bf16(xb[ks], B2[ks][0], c10, 0, 0, 0);
        c11 = __builtin_amdgcn_mfma_f32_16x16x32_bf16(xb[ks], B2[ks][1], c11, 0, 0, 0);
      }
#pragma unroll
      for (int r = 0; r < 4; ++r) {
        red[wave][r][lane]      = c00[r];
        red[wave][4 + r][lane]  = c01[r];
        red[wave][8 + r][lane]  = c10[r];
        red[wave][12 + r][lane] = c11[r];
      }
      __syncthreads();   // gates epilogue behind WG-wide union of h-waits
      float g0 = b2a, g1 = b2b;
#pragma unroll
      for (int w = 0; w < 8; ++w) {
        g0 += red[w][ridx][lidx0];
        g1 += red[w][ridx][lidx0 + 1];
      }
      const int c0 = n0 + nl;
      if (t < NSTEPS - 1) {                      // here chunk < 62 (doP2)
        float pv0, pv1;
        if (c0 < 64) {                           // shifted-in x_t (exact fp32)
          pv0 = inp[((size_t)t * NB + mrow) * 64 + c0];
          pv1 = inp[((size_t)t * NB + mrow) * 64 + c0 + 1];
        } else if (t > 0) {                      // fp32 master, chunk-2 covered by union
          union { u64 u; float f[2]; } pu;
          pu.u = ald64(SfOld + (size_t)mrow * SS + (c0 - 64));
          pv0 = pu.f[0]; pv1 = pu.f[1];
        } else { pv0 = 0.f; pv1 = 0.f; }
        float sv0 = 0.9f * pv0 + 0.1f * g0;
        float sv1 = 0.9f * pv1 + 0.1f * g1;
        union { float f[2]; u64 u; } su; su.f[0] = sv0; su.f[1] = sv1;
        ast64(SfNew + (size_t)mrow * SS + c0, su.u);
        unsigned sb = (unsigned)(unsigned short)f2bf(sv0)
                    | ((unsigned)(unsigned short)f2bf(sv1) << 16);
        ast32((unsigned*)(SbNew + (size_t)mrow * SS + c0), sb);
        asm volatile("s_waitcnt vmcnt(0)" ::: "memory");
        if (lane == 0)
          ast32(sflags + (chunk * 8 + wave) * 4, (unsigned)t + 1);
      } else {                                   // t==127, chunk>=62: emit out
        union { u64 u; float f[2]; } pu;
        pu.u = ald64(SfOld + (size_t)mrow * SS + (c0 - 64));
        float* po = out + (size_t)mrow * 64 + (c0 - SS);
        po[0] = 0.9f * pu.f[0] + 0.1f * g0;
        po[1] = 0.9f * pu.f[1] + 0.1f * g1;
      }
      __syncthreads();   // red reuse barrier before next phase-1
    }
  }
}

extern "C" void kernel_launch(void* const* d_in, const int* in_sizes, int n_in,
                              void* d_out, int out_size, void* d_ws, size_t ws_size,
                              hipStream_t stream)
{
  (void)in_sizes; (void)n_in; (void)out_size; (void)ws_size;
  const float* inp = (const float*)d_in[0];
  const float* W1  = (const float*)d_in[1];
  const float* b1  = (const float*)d_in[2];
  const float* W2  = (const float*)d_in[3];
  const float* b2  = (const float*)d_in[4];
  float* out = (float*)d_out;

  hipMemsetAsync(d_ws, 0, 65536, stream);  // flag arrays
  resrnn_kernel<<<dim3(256), dim3(512), 0, stream>>>(
      inp, W1, b1, W2, b2, out, (unsigned char*)d_ws);
}